// Round 13
// baseline (362.967 us; speedup 1.0000x reference)
//
#include <hip/hip_runtime.h>
#include <hip/hip_bf16.h>

typedef __hip_bfloat16 bf16;

#define N_NODES 100000
#define N_EDGES 1600000
#define D_IN    100
#define D_HID   50
#define N_REL   237
#define N_REL2  474
#define N_CLASS 50

// binned scatter: 196 buckets of 512 nodes
#define NBUCK    196
#define BSHIFT   9
#define BCAP     10240                // mean 8.2K -> huge headroom
#define BIN_EPB  1024
#define BIN_BLKS ((N_EDGES + BIN_EPB - 1) / BIN_EPB)   // 1563

// k_mid grid partition: bin | pack1 | pack2 | rel
#define MID_PACK1_BLKS 160            // 4 ksteps * 10240 / 256
#define MID_PACK2_BLKS 80
#define MID_REL_BLKS   474
#define MID_TOTAL (BIN_BLKS + MID_PACK1_BLKS + MID_PACK2_BLKS + MID_REL_BLKS)

#define GEMM_BLKS ((N_NODES + 31) / 32)   // 3125 (32-row tiles)

// C-tile LDS leading dim: 324 (row step = 2 banks; quads 8 banks apart -> 2-way free)
#define CST 324

// reduce: 4 waves/block, 2 rows/wave -> 8 rows/block
#define RED_BLKS (N_NODES / 8)        // 12500, exact

typedef __attribute__((ext_vector_type(8))) short short8;
typedef __attribute__((ext_vector_type(4))) float f32x4;
typedef __attribute__((ext_vector_type(2))) float f32x2;

__device__ __forceinline__ float b2f(bf16 v) { return __bfloat162float(v); }
__device__ __forceinline__ bf16  f2b(float v) { return __float2bfloat16(v); }

// dual-dtype raw weight loader (flag: 1 = bf16, 0 = fp32)
__device__ __forceinline__ float ldw(const void* p, int idx, int isbf) {
    return isbf ? b2f(((const bf16*)p)[idx]) : ((const float*)p)[idx];
}

#if __has_builtin(__builtin_amdgcn_cvt_f32_fp8) && __has_builtin(__builtin_amdgcn_cvt_pk_fp8_f32)
#define F8_HW 1
#endif
#if __has_builtin(__builtin_amdgcn_cvt_pk_f32_fp8)
#define F8PK_HW 1
#endif

// ---- fp8 e4m3 (OCP, gfx950 HW) helpers ----
__device__ __forceinline__ float f8tof(unsigned u) {
#ifdef F8_HW
    return __builtin_amdgcn_cvt_f32_fp8((int)u, 0);
#else
    unsigned s = u >> 7, e = (u >> 3) & 0xF, m = u & 7;
    float v;
    if (e == 0) v = (float)m * 0.001953125f;
    else        v = (float)(8 + m) * __builtin_ldexpf(1.f, (int)e - 10);
    return s ? -v : v;
#endif
}

#ifdef F8_HW
#define F8SEL(u, s) __builtin_amdgcn_cvt_f32_fp8((int)(u), (s))
#else
#define F8SEL(u, s) f8tof(((u) >> (8 * (s))) & 0xFFu)
#endif

template <bool HI>
__device__ __forceinline__ f32x2 f8pk(unsigned u) {
#ifdef F8PK_HW
    return __builtin_amdgcn_cvt_pk_f32_fp8((int)u, HI);
#else
    f32x2 r;
    r.x = F8SEL(u, HI ? 2 : 0);
    r.y = F8SEL(u, HI ? 3 : 1);
    return r;
#endif
}

__device__ __forceinline__ unsigned f8enc_sw(float v) {
    unsigned bits = __float_as_uint(v);
    unsigned s = bits >> 31;
    float a = fabsf(v);
    if (a < 0.0009765625f) return s << 7;
    if (a >= 448.f) return (s << 7) | 0x7E;
    int E = (int)((bits >> 23) & 0xFF) - 127;
    unsigned m = bits & 0x7FFFFF;
    if (E < -6) {
        int q = (int)rintf(a * 512.f);
        if (q > 7) q = 7;
        return (s << 7) | (unsigned)q;
    }
    unsigned lsb = (m >> 20) & 1, rnd = (m >> 19) & 1;
    unsigned sticky = (m & 0x7FFFF) ? 1u : 0u;
    unsigned m3 = (m >> 20) + (rnd & (sticky | lsb));
    if (m3 == 8) { m3 = 0; E += 1; }
    if (E > 8) return (s << 7) | 0x7E;
    return (s << 7) | ((unsigned)(E + 7) << 3) | m3;
}

__device__ __forceinline__ unsigned pk4_f8(float v0, float v1, float v2, float v3) {
#ifdef F8_HW
    int p = __builtin_amdgcn_cvt_pk_fp8_f32(v0, v1, 0, false);
    p = __builtin_amdgcn_cvt_pk_fp8_f32(v2, v3, p, true);
    return (unsigned)p;
#else
    return f8enc_sw(v0) | (f8enc_sw(v1) << 8) | (f8enc_sw(v2) << 16) | (f8enc_sw(v3) << 24);
#endif
}

// ---- per-block dtype self-detection (replaces the serial k_detect launch).
// 1 = bf16, 0 = fp32; samples first 4096 values of x_raw (L2-hot).
__device__ __forceinline__ int detect_flag(const unsigned short* __restrict__ xr) {
    __shared__ int sh[256];
    int tid = threadIdx.x;
    int cnt = 0;
    for (int i = tid; i < 4096; i += 256) {
        unsigned short u = xr[2 * i];
        unsigned e = (u >> 7) & 0xFF;
        bool pl = (e >= 107 && e <= 132) || ((u & 0x7FFF) == 0);
        cnt += pl ? 1 : 0;
    }
    sh[tid] = cnt;
    __syncthreads();
    for (int s = 128; s > 0; s >>= 1) {
        if (tid < s) sh[tid] += sh[tid + s];
        __syncthreads();
    }
    return (sh[0] >= 3072) ? 1 : 0;
}

// ---- bin job: per-block LDS counting-sort of 1024 edges into bucket staging
__device__ __forceinline__ void job_bin(int blk, const int* __restrict__ src,
                                        const int* __restrict__ dst,
                                        const int* __restrict__ et,
                                        unsigned* __restrict__ bucketFill,
                                        unsigned long long* __restrict__ staging) {
    __shared__ unsigned lhist[NBUCK];
    __shared__ unsigned lstart[NBUCK];
    __shared__ unsigned gbase[NBUCK];
    __shared__ unsigned scan_tmp[NBUCK];
    __shared__ unsigned long long lval[BIN_EPB];
    __shared__ unsigned ltgt[BIN_EPB];
    int tid = threadIdx.x;
    int base = blk * BIN_EPB;
    int n = N_EDGES - base; if (n > BIN_EPB) n = BIN_EPB;

    for (int i = tid; i < NBUCK; i += 256) lhist[i] = 0;
    __syncthreads();

    unsigned bb[4], rr[4];
    unsigned long long vv[4];
#pragma unroll
    for (int j = 0; j < 4; ++j) {
        int i = j * 256 + tid;
        bb[j] = 0xFFFFFFFFu;
        if (i < n) {
            int e = base + i;
            unsigned d = (unsigned)dst[e];
            unsigned b = d >> BSHIFT;
            bb[j] = b;
            rr[j] = atomicAdd(&lhist[b], 1u);
            vv[j] = ((unsigned long long)d << 32) |
                    (unsigned long long)((unsigned)src[e] | ((unsigned)et[e] << 17));
        }
    }
    __syncthreads();
    unsigned v0 = (tid < NBUCK) ? lhist[tid] : 0;
    if (tid < NBUCK) scan_tmp[tid] = v0;
    __syncthreads();
    for (int s = 1; s < NBUCK; s <<= 1) {
        unsigned t = 0;
        if (tid < NBUCK && tid >= (unsigned)s) t = scan_tmp[tid - s];
        __syncthreads();
        if (tid < NBUCK) scan_tmp[tid] += t;
        __syncthreads();
    }
    if (tid < NBUCK) {
        lstart[tid] = scan_tmp[tid] - v0;
        gbase[tid] = (v0 > 0) ? atomicAdd(&bucketFill[tid], v0) : 0u;
    }
    __syncthreads();
#pragma unroll
    for (int j = 0; j < 4; ++j) {
        if (bb[j] != 0xFFFFFFFFu) {
            unsigned pos = lstart[bb[j]] + rr[j];
            unsigned off = gbase[bb[j]] + rr[j];
            lval[pos] = vv[j];
            ltgt[pos] = (off < BCAP) ? (bb[j] * BCAP + off) : 0xFFFFFFFFu;
        }
    }
    __syncthreads();
    for (int i = tid; i < n; i += 256) {
        unsigned t = ltgt[i];
        if (t != 0xFFFFFFFFu) staging[t] = lval[i];
    }
}

// ---- pack job body: basis[5][KL][50] + root[KL][50] -> MFMA B-fragment order
__device__ __forceinline__ void job_pack(int blk, const void* basis, const void* root,
                                         bf16* Wb, int KL, int isbf) {
    int g = blk * 256 + threadIdx.x;
    int ks = g / 10240;
    int r = g - ks * 10240;
    int ct = r >> 9;
    int r2 = r & 511;
    int l = r2 >> 3, j = r2 & 7;
    int k = ks * 32 + ((l >> 4) << 3) + j;
    int n = ct * 16 + (l & 15);
    float v = 0.f;
    if (k < KL && n < 300) {
        if (n < 250) { int b = n / 50, f = n - b * 50; v = ldw(basis, (b * KL + k) * 50 + f, isbf); }
        else         v = ldw(root, k * 50 + (n - 250), isbf);
    }
    Wb[g] = f2b(v);
}

// ---- rel job: per-type rt1/rt2/c8 tables from raw weights (templated dtype)
template<int ISBF>
__device__ __forceinline__ void job_rel(int t,
        const void* __restrict__ rel_emb, const void* __restrict__ rel_w,
        const void* __restrict__ basis1, const void* __restrict__ comp1,
        const void* __restrict__ basis2, const void* __restrict__ comp2,
        float* __restrict__ rt1, float* __restrict__ rt2,
        float* __restrict__ c81, float* __restrict__ c82) {
    int tid = threadIdx.x;
    __shared__ float rf[D_IN];
    __shared__ float r2s[D_HID];
    int tm = (t >= N_REL) ? t - N_REL : t;
    if (tid < D_IN) rf[tid] = ldw(rel_emb, tm * D_IN + tid, ISBF);
    if (tid < 8) {
        c81[t * 8 + tid] = (tid < 5) ? ldw(comp1, t * 5 + tid, ISBF) : 0.f;
        c82[t * 8 + tid] = (tid < 5) ? ldw(comp2, t * 5 + tid, ISBF) : 0.f;
    }
    __syncthreads();
    if (tid < 50) {
        int f = tid;
        float a = 0.f;
        for (int b = 0; b < 5; ++b) {
            float cb = ldw(comp1, t * 5 + b, ISBF);
            float s = 0.f;
            for (int k = 0; k < D_IN; ++k) s += rf[k] * ldw(basis1, (b * D_IN + k) * 50 + f, ISBF);
            a += cb * s;
        }
        rt1[t * 50 + f] = a;
        float s2 = 0.f;
        for (int k = 0; k < D_IN; ++k) s2 += rf[k] * ldw(rel_w, k * 50 + f, ISBF);
        r2s[f] = s2;
    }
    __syncthreads();
    if (tid < 50) {
        int f = tid;
        float a = 0.f;
        for (int b = 0; b < 5; ++b) {
            float cb = ldw(comp2, t * 5 + b, ISBF);
            float s = 0.f;
            for (int k = 0; k < 50; ++k) s += r2s[k] * ldw(basis2, (b * 50 + k) * 50 + f, ISBF);
            a += cb * s;
        }
        rt2[t * 50 + f] = a;
    }
}

// ================= fused mid kernel: bin | pack1 | pack2 | rel ===============
// pack/rel blocks self-detect dtype (no serial k_detect launch); the first
// pack1 block also publishes flag[0] for downstream kernels (stream-ordered).
__global__ __launch_bounds__(256) void k_mid(const int* __restrict__ srcp,
                                             const int* __restrict__ dstp,
                                             const int* __restrict__ etp,
                                             unsigned* __restrict__ bucketFill,
                                             unsigned long long* __restrict__ staging,
                                             const void* __restrict__ x_raw,
                                             int* __restrict__ flag,
                                             const void* rel_emb, const void* rel_w,
                                             const void* basis1, const void* comp1,
                                             const void* root1,
                                             const void* basis2, const void* comp2,
                                             const void* root2,
                                             bf16* __restrict__ Wb1, bf16* __restrict__ Wb2,
                                             float* __restrict__ rt1, float* __restrict__ rt2,
                                             float* __restrict__ c81, float* __restrict__ c82) {
    int blk = blockIdx.x;
    if (blk < BIN_BLKS) { job_bin(blk, srcp, dstp, etp, bucketFill, staging); return; }
    blk -= BIN_BLKS;
    int isbf = detect_flag((const unsigned short*)x_raw);
    if (blk < MID_PACK1_BLKS) {
        if (blk == 0 && threadIdx.x == 0) flag[0] = isbf;
        job_pack(blk, basis1, root1, Wb1, D_IN, isbf);
        return;
    }
    blk -= MID_PACK1_BLKS;
    if (blk < MID_PACK2_BLKS) { job_pack(blk, basis2, root2, Wb2, D_HID, isbf); return; }
    blk -= MID_PACK2_BLKS;
    if (isbf) job_rel<1>(blk, rel_emb, rel_w, basis1, comp1, basis2, comp2, rt1, rt2, c81, c82);
    else      job_rel<0>(blk, rel_emb, rel_w, basis1, comp1, basis2, comp2, rt1, rt2, c81, c82);
}

// ---- per-bucket CSR build, 256-thread version (shares LDS with gemm) --------
__device__ __forceinline__ void job_bucket(int b, char* shraw,
        const unsigned long long* __restrict__ staging,
        const unsigned* __restrict__ bucketFill,
        int* __restrict__ offs, unsigned* __restrict__ se) {
    unsigned* hist = (unsigned*)shraw;          // [512]
    unsigned* excl = hist + 512;                // [512]
    unsigned* bfs  = excl + 512;                // [256] (196 used)
    unsigned* tmp  = bfs + 256;                 // [256]
    int tid = threadIdx.x;

    if (tid < NBUCK) {
        unsigned c = bucketFill[tid];
        bfs[tid] = (c > BCAP) ? BCAP : c;
    }
    hist[tid] = 0; hist[tid + 256] = 0;
    __syncthreads();
    // inclusive scan of 196 bucket totals
    for (int s = 1; s < NBUCK; s <<= 1) {
        unsigned t = 0;
        if (tid < NBUCK && tid >= s) t = bfs[tid - s];
        __syncthreads();
        if (tid < NBUCK) bfs[tid] += t;
        __syncthreads();
    }
    unsigned base = (b == 0) ? 0u : bfs[b - 1];
    unsigned cnt = bfs[b] - base;

    const unsigned long long* p = staging + (size_t)b * BCAP;
    // pass 1: per-node histogram (local id = dst & 511)
    for (unsigned i = tid; i < cnt; i += 256) {
        unsigned d = (unsigned)(p[i] >> 32);
        atomicAdd(&hist[d & 511], 1u);
    }
    __syncthreads();
    // scan 512 node counts with 256 threads (pairwise)
    unsigned h0 = hist[2 * tid], h1 = hist[2 * tid + 1];
    tmp[tid] = h0 + h1;
    __syncthreads();
    for (int s = 1; s < 256; s <<= 1) {
        unsigned t = (tid >= s) ? tmp[tid - s] : 0u;
        __syncthreads();
        tmp[tid] += t;
        __syncthreads();
    }
    unsigned pe = (tid > 0) ? tmp[tid - 1] : 0u;
    excl[2 * tid]     = pe;
    excl[2 * tid + 1] = pe + h0;
    hist[2 * tid] = 0; hist[2 * tid + 1] = 0;   // reset for rank pass
    __syncthreads();

#pragma unroll
    for (int q = 0; q < 2; ++q) {
        int li = 2 * tid + q;
        int node = b * 512 + li;
        if (node < N_NODES) offs[node] = (int)(base + excl[li]);
        if (node == N_NODES - 1) offs[N_NODES] = (int)(base + cnt);
    }

    // pass 2: scatter with per-node rank
    for (unsigned i = tid; i < cnt; i += 256) {
        unsigned long long v = p[i];
        unsigned ld = ((unsigned)(v >> 32)) & 511u;
        unsigned r = atomicAdd(&hist[ld], 1u);
        se[base + excl[ld] + r] = (unsigned)v;
    }
}

// ---- MFMA GEMM (+ fused bucket blocks, scheduled FIRST): X @ Wb -> Y8 + R
// 32-row block, 4 waves = 2(row) x 2(col-half). Each wave: acc[10] = 40 AGPR.
template<int KP, bool ZT, bool RAWX>
__global__ __launch_bounds__(256, 4) void k_gemm_b(const void* __restrict__ Xraw,
                                                const int* __restrict__ flag,
                                                const bf16* __restrict__ Wb,
                                                unsigned char* __restrict__ Y8,
                                                bf16* __restrict__ R, int M,
                                                const int* __restrict__ tgt,
                                                const unsigned long long* __restrict__ staging,
                                                const unsigned* __restrict__ bucketFill,
                                                int* __restrict__ offs,
                                                unsigned* __restrict__ se,
                                                int nbuckBlks) {
    constexpr int AP = KP + 8;        // padded A-tile leading dim (bf16 elems)
    constexpr int CBYTES = 32 * CST * 2;   // 20736
    constexpr int ABYTES = 32 * AP * 2;
    __shared__ __attribute__((aligned(16))) char shraw[CBYTES + ABYTES];
    if ((int)blockIdx.x < nbuckBlks) {
        job_bucket(blockIdx.x, shraw, staging, bucketFill, offs, se);
        return;
    }
    int gblk = blockIdx.x - nbuckBlks;
    bf16* smemC = (bf16*)shraw;
    bf16* smemA = (bf16*)(shraw + CBYTES);
    int tid = threadIdx.x;
    int w = tid >> 6, lane = tid & 63;
    int quad = lane >> 4, cIn = lane & 15;
    int rw = w & 1, cw = w >> 1;      // row-wave, col-half wave
    int base_row = gblk * 32;

    if (RAWX) {
        int isbf = flag[0];
        // 32 rows x 128 cols (zero-pad 100..127), 4 cols/thread (8/16B loads)
        for (int i = tid; i < 32 * 32; i += 256) {
            int r = i >> 5, c4 = (i & 31) << 2;
            int row = base_row + r; if (row > M - 1) row = M - 1;
            unsigned p0 = 0, p1 = 0;
            if (c4 < 100) {
                if (isbf) {
                    const unsigned* xp = (const unsigned*)((const unsigned short*)Xraw + (size_t)row * 100 + c4);
                    p0 = xp[0]; p1 = xp[1];
                } else {
                    const float* xp = (const float*)Xraw + (size_t)row * 100 + c4;
                    float4 v = *(const float4*)xp;
                    bf16 b0 = f2b(v.x), b1 = f2b(v.y), b2 = f2b(v.z), b3 = f2b(v.w);
                    p0 = (unsigned)*(unsigned short*)&b0 | ((unsigned)*(unsigned short*)&b1 << 16);
                    p1 = (unsigned)*(unsigned short*)&b2 | ((unsigned)*(unsigned short*)&b3 << 16);
                }
            }
            unsigned* dstp2 = (unsigned*)(&smemA[r * AP + c4]);
            dstp2[0] = p0; dstp2[1] = p1;
        }
    } else {
        const bf16* X = (const bf16*)Xraw;
        const int TOT = 32 * KP / 8;
        for (int i = tid; i < TOT; i += 256) {
            int e8 = i * 8;
            int r = e8 / KP, c = e8 - r * KP;
            int row = base_row + r; if (row > M - 1) row = M - 1;
            *(uint4*)(&smemA[r * AP + c]) = *(const uint4*)(&X[(size_t)row * KP + c]);
        }
    }
    __syncthreads();

    f32x4 acc[10];
#pragma unroll
    for (int i = 0; i < 10; ++i) acc[i] = (f32x4){0.f, 0.f, 0.f, 0.f};

#pragma unroll
    for (int ks = 0; ks < KP / 32; ++ks) {
        short8 a = *(const short8*)(&smemA[(rw * 16 + cIn) * AP + ks * 32 + quad * 8]);
#pragma unroll
        for (int ct = 0; ct < 10; ++ct) {
            short8 b = *(const short8*)(&Wb[(size_t)((ks * 20 + cw * 10 + ct) * 64 + lane) * 8]);
            acc[ct] = __builtin_amdgcn_mfma_f32_16x16x32_bf16(a, b, acc[ct], 0, 0, 0);
        }
    }

#pragma unroll
    for (int ct = 0; ct < 10; ++ct)
#pragma unroll
        for (int r = 0; r < 4; ++r)
            smemC[(rw * 16 + quad * 4 + r) * CST + (cw * 10 + ct) * 16 + cIn] = f2b(acc[ct][r]);
    __syncthreads();

    int tv = -1;
    if (ZT) tv = tgt[0];
    int valid = M - base_row; if (valid > 32) valid = 32;

    for (int i = tid; i < valid * 64; i += 256) {
        int r = i >> 6, u = i & 63;
        int row = base_row + r;
        unsigned pbits;
        if (u < 50) {
            pbits = pk4_f8(b2f(smemC[r * CST + u]),       b2f(smemC[r * CST + 50 + u]),
                           b2f(smemC[r * CST + 100 + u]), b2f(smemC[r * CST + 150 + u]));
        } else if (u < 63) {
            int fb = (u - 50) * 4;
            float v0 = (fb + 0 < 50) ? b2f(smemC[r * CST + 200 + fb + 0]) : 0.f;
            float v1 = (fb + 1 < 50) ? b2f(smemC[r * CST + 200 + fb + 1]) : 0.f;
            float v2 = (fb + 2 < 50) ? b2f(smemC[r * CST + 200 + fb + 2]) : 0.f;
            float v3 = (fb + 3 < 50) ? b2f(smemC[r * CST + 200 + fb + 3]) : 0.f;
            pbits = pk4_f8(v0, v1, v2, v3);
        } else {
            pbits = 0u;
        }
        if (ZT && row == tv) pbits = 0u;
        *(unsigned*)(Y8 + (size_t)row * 256 + u * 4) = pbits;
    }
    for (int i = tid; i < valid * 32; i += 256) {
        int r = i >> 5, cu = i & 31;
        int row = base_row + r;
        int j0 = cu * 2, j1 = j0 + 1;
        unsigned short ua = (j0 < 50) ? *(const unsigned short*)&smemC[r * CST + 250 + j0] : 0;
        unsigned short ub = (j1 < 50) ? *(const unsigned short*)&smemC[r * CST + 250 + j1] : 0;
        unsigned u = (unsigned)ua | ((unsigned)ub << 16);
        if (ZT && row == tv) u = 0u;
        *(unsigned*)((unsigned short*)R + (size_t)row * 64 + j0) = u;
    }
}

// ================= per-node gather-reduce (no atomics) =======================
__device__ __forceinline__ void edge_body(unsigned p, int f,
        const unsigned char* __restrict__ Y8,
        const float* __restrict__ c8, const float* __restrict__ rt,
        f32x2& acc2, float& accS) {
    unsigned ps = (unsigned)__builtin_amdgcn_readfirstlane((int)p);
    int s_ = (int)(ps & 0x1FFFFu);
    int t_ = (int)(ps >> 17);
    const unsigned char* yr = Y8 + (size_t)s_ * 256;
    unsigned a4 = *(const unsigned*)(yr + 4 * f);
    float y4 = f8tof(yr[200 + f]);
    const float* cp = c8 + t_ * 8;
    f32x4 c03 = *(const f32x4*)cp;
    float c4 = cp[4];
    float rv = rt[t_ * 50 + f];
    f32x2 y01 = f8pk<false>(a4);
    f32x2 y23 = f8pk<true>(a4);
    f32x2 cA; cA.x = c03.x; cA.y = c03.y;
    f32x2 cB; cB.x = c03.z; cB.y = c03.w;
    acc2 += cA * y01;
    acc2 += cB * y23;
    accS += rv + c4 * y4;
}

// Two consecutive rows per wave, 4-deep interleave, with scalar-prefetch of
// the NEXT group's se payloads (hides the s_load L2 latency that was exposed
// at every group head). Accumulation order identical to the proven form.
__device__ __forceinline__ void pair_reduce(const int* __restrict__ off,
        const unsigned int* __restrict__ se, const float* __restrict__ c8,
        const float* __restrict__ rt, const unsigned char* __restrict__ Y8,
        int rowA, int f, float& outA, float& outB, float& cntA, float& cntB) {
    int e0 = __builtin_amdgcn_readfirstlane(off[rowA]);
    int e1 = __builtin_amdgcn_readfirstlane(off[rowA + 1]);
    int e2 = __builtin_amdgcn_readfirstlane(off[rowA + 2]);
    f32x2 a2A; a2A.x = 0.f; a2A.y = 0.f;
    f32x2 a2B; a2B.x = 0.f; a2B.y = 0.f;
    float sA = 0.f, sB = 0.f;
    int eA = e0, eB = e1;
    bool have = (eA + 4 <= e1) && (eB + 4 <= e2);
    unsigned pA0 = 0, pA1 = 0, pA2 = 0, pA3 = 0;
    unsigned pB0 = 0, pB1 = 0, pB2 = 0, pB3 = 0;
    if (have) {
        pA0 = se[eA]; pA1 = se[eA + 1]; pA2 = se[eA + 2]; pA3 = se[eA + 3];
        pB0 = se[eB]; pB1 = se[eB + 1]; pB2 = se[eB + 2]; pB3 = se[eB + 3];
    }
    while (have) {
        int nA = eA + 4, nB = eB + 4;
        bool nh = (nA + 4 <= e1) && (nB + 4 <= e2);
        unsigned qA0 = 0, qA1 = 0, qA2 = 0, qA3 = 0;
        unsigned qB0 = 0, qB1 = 0, qB2 = 0, qB3 = 0;
        if (nh) {
            qA0 = se[nA]; qA1 = se[nA + 1]; qA2 = se[nA + 2]; qA3 = se[nA + 3];
            qB0 = se[nB]; qB1 = se[nB + 1]; qB2 = se[nB + 2]; qB3 = se[nB + 3];
        }
        edge_body(pA0, f, Y8, c8, rt, a2A, sA);
        edge_body(pB0, f, Y8, c8, rt, a2B, sB);
        edge_body(pA1, f, Y8, c8, rt, a2A, sA);
        edge_body(pB1, f, Y8, c8, rt, a2B, sB);
        edge_body(pA2, f, Y8, c8, rt, a2A, sA);
        edge_body(pB2, f, Y8, c8, rt, a2B, sB);
        edge_body(pA3, f, Y8, c8, rt, a2A, sA);
        edge_body(pB3, f, Y8, c8, rt, a2B, sB);
        pA0 = qA0; pA1 = qA1; pA2 = qA2; pA3 = qA3;
        pB0 = qB0; pB1 = qB1; pB2 = qB2; pB3 = qB3;
        eA = nA; eB = nB; have = nh;
    }
    while (eA + 4 <= e1) {
        unsigned p0 = se[eA], p1 = se[eA + 1], p2 = se[eA + 2], p3 = se[eA + 3];
        edge_body(p0, f, Y8, c8, rt, a2A, sA);
        edge_body(p1, f, Y8, c8, rt, a2A, sA);
        edge_body(p2, f, Y8, c8, rt, a2A, sA);
        edge_body(p3, f, Y8, c8, rt, a2A, sA);
        eA += 4;
    }
    while (eB + 4 <= e2) {
        unsigned p0 = se[eB], p1 = se[eB + 1], p2 = se[eB + 2], p3 = se[eB + 3];
        edge_body(p0, f, Y8, c8, rt, a2B, sB);
        edge_body(p1, f, Y8, c8, rt, a2B, sB);
        edge_body(p2, f, Y8, c8, rt, a2B, sB);
        edge_body(p3, f, Y8, c8, rt, a2B, sB);
        eB += 4;
    }
    for (; eA < e1; ++eA) edge_body(se[eA], f, Y8, c8, rt, a2A, sA);
    for (; eB < e2; ++eB) edge_body(se[eB], f, Y8, c8, rt, a2B, sB);
    outA = a2A.x + a2A.y + sA;
    outB = a2B.x + a2B.y + sB;
    float nA = (float)(e1 - e0); cntA = nA > 1.f ? nA : 1.f;
    float nB = (float)(e2 - e1); cntB = nB > 1.f ? nB : 1.f;
}

// Layer 1: h[row][0..63] = mean_agg + x@root (R) + bias (cols>=50 zero)
__global__ __launch_bounds__(256) void k_reduce1(const int* __restrict__ off,
                                                 const unsigned int* __restrict__ se,
                                                 const float* __restrict__ c8,
                                                 const float* __restrict__ rt,
                                                 const unsigned char* __restrict__ Y8,
                                                 const bf16* __restrict__ R,
                                                 const void* __restrict__ bias_raw,
                                                 const int* __restrict__ flag,
                                                 bf16* __restrict__ h) {
    int wid = threadIdx.x >> 6, lane = threadIdx.x & 63;
    int rowA = __builtin_amdgcn_readfirstlane(blockIdx.x * 8 + wid * 2);
    int f = (lane < 50) ? lane : 49;
    float accA, accB, cntA, cntB;
    pair_reduce(off, se, c8, rt, Y8, rowA, f, accA, accB, cntA, cntB);
    float bv = ldw(bias_raw, f, flag[0]);
    float vA = accA / cntA + b2f(R[(size_t)rowA * 64 + f]) + bv;
    float vB = accB / cntB + b2f(R[(size_t)(rowA + 1) * 64 + f]) + bv;
    h[(size_t)rowA * 64 + lane]       = f2b(lane < 50 ? vA : 0.f);
    h[(size_t)(rowA + 1) * 64 + lane] = f2b(lane < 50 ? vB : 0.f);
}

__device__ __forceinline__ void softmax_store(float acc, float cnt, int row, int f,
        int lane, const bf16* __restrict__ R, float bv,
        int isbf, void* __restrict__ out) {
    float v = -INFINITY;
    if (lane < 50)
        v = acc / cnt + b2f(R[(size_t)row * 64 + f]) + bv;
    float m = v;
    for (int o = 32; o > 0; o >>= 1) m = fmaxf(m, __shfl_xor(m, o));
    float ex = (lane < 50) ? expf(v - m) : 0.f;
    float s = ex;
    for (int o = 32; o > 0; o >>= 1) s += __shfl_xor(s, o);
    float res = v - m - logf(s);
    if (lane < 50) {
        if (isbf) ((bf16*)out)[row * 50 + f] = f2b(res);
        else      ((float*)out)[row * 50 + f] = res;
    }
}

// Layer 2: same reduce + log_softmax epilogue; dual-dtype output store.
__global__ __launch_bounds__(256) void k_reduce2(const int* __restrict__ off,
                                                 const unsigned int* __restrict__ se,
                                                 const float* __restrict__ c8,
                                                 const float* __restrict__ rt,
                                                 const unsigned char* __restrict__ Y8,
                                                 const bf16* __restrict__ R,
                                                 const void* __restrict__ bias_raw,
                                                 const int* __restrict__ flag,
                                                 void* __restrict__ out) {
    int wid = threadIdx.x >> 6, lane = threadIdx.x & 63;
    int rowA = __builtin_amdgcn_readfirstlane(blockIdx.x * 8 + wid * 2);
    int f = (lane < 50) ? lane : 49;
    float accA, accB, cntA, cntB;
    pair_reduce(off, se, c8, rt, Y8, rowA, f, accA, accB, cntA, cntB);
    int isbf = flag[0];
    float bv = ldw(bias_raw, f, isbf);
    softmax_store(accA, cntA, rowA, f, lane, R, bv, isbf, out);
    softmax_store(accB, cntB, rowA + 1, f, lane, R, bv, isbf, out);
}

extern "C" void kernel_launch(void* const* d_in, const int* in_sizes, int n_in,
                              void* d_out, int out_size, void* d_ws, size_t ws_size,
                              hipStream_t stream) {
    const void* x_raw = d_in[0];
    const int*  ei    = (const int*)d_in[1];
    const int*  et    = (const int*)d_in[2];
    const int*  tgt   = (const int*)d_in[3];
    const void* rel_emb = d_in[4];
    const void* rel_w   = d_in[5];
    const void* basis1  = d_in[6];
    const void* comp1   = d_in[7];
    const void* root1   = d_in[8];
    const void* bias1   = d_in[9];
    const void* basis2  = d_in[10];
    const void* comp2   = d_in[11];
    const void* root2   = d_in[12];
    const void* bias2   = d_in[13];

    char* wsp = (char*)d_ws;
    size_t off_b = 0;
    auto alloc = [&](size_t bytes) {
        void* p = wsp + off_b;
        off_b = (off_b + bytes + 255) & ~(size_t)255;
        return p;
    };
    unsigned char* Y8 = (unsigned char*)alloc((size_t)N_NODES * 256);       // 25.6 MB
    bf16*  R    = (bf16*) alloc((size_t)N_NODES * 64 * sizeof(bf16));       // 12.8 MB
    bf16*  h    = (bf16*) alloc((size_t)N_NODES * 64 * sizeof(bf16));       // 12.8 MB
    unsigned int* se = (unsigned int*)alloc((size_t)N_EDGES * sizeof(unsigned int)); // 6.4 MB
    unsigned long long* staging = (unsigned long long*)alloc((size_t)NBUCK * BCAP * 8); // 16 MB
    int*   offs = (int*)  alloc((size_t)(N_NODES + 1) * sizeof(int));
    unsigned* bucketFill = (unsigned*)alloc((size_t)NBUCK * sizeof(unsigned));
    bf16*  Wb1  = (bf16*) alloc((size_t)40960 * sizeof(bf16));
    bf16*  Wb2  = (bf16*) alloc((size_t)20480 * sizeof(bf16));
    float* rt1  = (float*)alloc((size_t)N_REL2 * 50 * sizeof(float));
    float* rt2  = (float*)alloc((size_t)N_REL2 * 50 * sizeof(float));
    float* c81  = (float*)alloc((size_t)N_REL2 * 8 * sizeof(float));
    float* c82  = (float*)alloc((size_t)N_REL2 * 8 * sizeof(float));
    int*   flag = (int*)  alloc(sizeof(int));

    const int* srcp = ei;
    const int* dstp = ei + N_EDGES;

    hipMemsetAsync(bucketFill, 0, (size_t)NBUCK * sizeof(unsigned), stream);

    // bin | pack1 | pack2 | rel (pack/rel self-detect dtype; pack1 blk0 writes flag)
    k_mid<<<MID_TOTAL, 256, 0, stream>>>(srcp, dstp, et, bucketFill, staging,
                                         x_raw, flag,
                                         rel_emb, rel_w, basis1, comp1, root1,
                                         basis2, comp2, root2,
                                         Wb1, Wb2, rt1, rt2, c81, c82);

    // Layer-1 GEMM (raw-x staging) fused with per-bucket CSR build (buckets first)
    k_gemm_b<128, true, true><<<GEMM_BLKS + NBUCK, 256, 0, stream>>>(
        x_raw, flag, Wb1, Y8, R, N_NODES, tgt, staging, bucketFill, offs, se, NBUCK);

    k_reduce1<<<RED_BLKS, 256, 0, stream>>>(offs, se, c81, rt1, Y8, R, bias1, flag, h);

    // Layer-2 GEMM (h is our aligned bf16 layout)
    k_gemm_b<64, false, false><<<GEMM_BLKS, 256, 0, stream>>>(
        h, flag, Wb2, Y8, R, N_NODES, nullptr, staging, bucketFill, offs, se, 0);

    k_reduce2<<<RED_BLKS, 256, 0, stream>>>(offs, se, c82, rt2, Y8, R, bias2, flag, d_out);
}

// Round 14
// 354.628 us; speedup vs baseline: 1.0235x; 1.0235x over previous
//
#include <hip/hip_runtime.h>
#include <hip/hip_bf16.h>

typedef __hip_bfloat16 bf16;

#define N_NODES 100000
#define N_EDGES 1600000
#define D_IN    100
#define D_HID   50
#define N_REL   237
#define N_REL2  474
#define N_CLASS 50

// binned scatter: 196 buckets of 512 nodes
#define NBUCK    196
#define BSHIFT   9
#define BCAP     10240                // mean 8.2K -> huge headroom
#define BIN_EPB  1024
#define BIN_BLKS ((N_EDGES + BIN_EPB - 1) / BIN_EPB)   // 1563

// k_mid grid partition: bin | pack1 | pack2 | rel
#define MID_PACK1_BLKS 160            // 4 ksteps * 10240 / 256
#define MID_PACK2_BLKS 80
#define MID_REL_BLKS   474
#define MID_TOTAL (BIN_BLKS + MID_PACK1_BLKS + MID_PACK2_BLKS + MID_REL_BLKS)

#define GEMM_BLKS ((N_NODES + 31) / 32)   // 3125 (32-row tiles)

// C-tile LDS leading dim: 324 (row step = 2 banks; quads 8 banks apart -> 2-way free)
#define CST 324

// reduce: 4 waves/block, 2 rows/wave -> 8 rows/block
#define RED_BLKS (N_NODES / 8)        // 12500, exact

typedef __attribute__((ext_vector_type(8))) short short8;
typedef __attribute__((ext_vector_type(4))) float f32x4;
typedef __attribute__((ext_vector_type(2))) float f32x2;

__device__ __forceinline__ float b2f(bf16 v) { return __bfloat162float(v); }
__device__ __forceinline__ bf16  f2b(float v) { return __float2bfloat16(v); }

// dual-dtype raw weight loader (flag: 1 = bf16, 0 = fp32)
__device__ __forceinline__ float ldw(const void* p, int idx, int isbf) {
    return isbf ? b2f(((const bf16*)p)[idx]) : ((const float*)p)[idx];
}

#if __has_builtin(__builtin_amdgcn_cvt_f32_fp8) && __has_builtin(__builtin_amdgcn_cvt_pk_fp8_f32)
#define F8_HW 1
#endif
#if __has_builtin(__builtin_amdgcn_cvt_pk_f32_fp8)
#define F8PK_HW 1
#endif

// ---- fp8 e4m3 (OCP, gfx950 HW) helpers ----
__device__ __forceinline__ float f8tof(unsigned u) {
#ifdef F8_HW
    return __builtin_amdgcn_cvt_f32_fp8((int)u, 0);
#else
    unsigned s = u >> 7, e = (u >> 3) & 0xF, m = u & 7;
    float v;
    if (e == 0) v = (float)m * 0.001953125f;
    else        v = (float)(8 + m) * __builtin_ldexpf(1.f, (int)e - 10);
    return s ? -v : v;
#endif
}

#ifdef F8_HW
#define F8SEL(u, s) __builtin_amdgcn_cvt_f32_fp8((int)(u), (s))
#else
#define F8SEL(u, s) f8tof(((u) >> (8 * (s))) & 0xFFu)
#endif

template <bool HI>
__device__ __forceinline__ f32x2 f8pk(unsigned u) {
#ifdef F8PK_HW
    return __builtin_amdgcn_cvt_pk_f32_fp8((int)u, HI);
#else
    f32x2 r;
    r.x = F8SEL(u, HI ? 2 : 0);
    r.y = F8SEL(u, HI ? 3 : 1);
    return r;
#endif
}

__device__ __forceinline__ unsigned f8enc_sw(float v) {
    unsigned bits = __float_as_uint(v);
    unsigned s = bits >> 31;
    float a = fabsf(v);
    if (a < 0.0009765625f) return s << 7;
    if (a >= 448.f) return (s << 7) | 0x7E;
    int E = (int)((bits >> 23) & 0xFF) - 127;
    unsigned m = bits & 0x7FFFFF;
    if (E < -6) {
        int q = (int)rintf(a * 512.f);
        if (q > 7) q = 7;
        return (s << 7) | (unsigned)q;
    }
    unsigned lsb = (m >> 20) & 1, rnd = (m >> 19) & 1;
    unsigned sticky = (m & 0x7FFFF) ? 1u : 0u;
    unsigned m3 = (m >> 20) + (rnd & (sticky | lsb));
    if (m3 == 8) { m3 = 0; E += 1; }
    if (E > 8) return (s << 7) | 0x7E;
    return (s << 7) | ((unsigned)(E + 7) << 3) | m3;
}

__device__ __forceinline__ unsigned pk4_f8(float v0, float v1, float v2, float v3) {
#ifdef F8_HW
    int p = __builtin_amdgcn_cvt_pk_fp8_f32(v0, v1, 0, false);
    p = __builtin_amdgcn_cvt_pk_fp8_f32(v2, v3, p, true);
    return (unsigned)p;
#else
    return f8enc_sw(v0) | (f8enc_sw(v1) << 8) | (f8enc_sw(v2) << 16) | (f8enc_sw(v3) << 24);
#endif
}

// ---- per-block dtype self-detection (replaces the serial k_detect launch).
// 1 = bf16, 0 = fp32; samples first 4096 values of x_raw (L2-hot).
__device__ __forceinline__ int detect_flag(const unsigned short* __restrict__ xr) {
    __shared__ int sh[256];
    int tid = threadIdx.x;
    int cnt = 0;
    for (int i = tid; i < 4096; i += 256) {
        unsigned short u = xr[2 * i];
        unsigned e = (u >> 7) & 0xFF;
        bool pl = (e >= 107 && e <= 132) || ((u & 0x7FFF) == 0);
        cnt += pl ? 1 : 0;
    }
    sh[tid] = cnt;
    __syncthreads();
    for (int s = 128; s > 0; s >>= 1) {
        if (tid < s) sh[tid] += sh[tid + s];
        __syncthreads();
    }
    return (sh[0] >= 3072) ? 1 : 0;
}

// ---- bin job: per-block LDS counting-sort of 1024 edges into bucket staging
__device__ __forceinline__ void job_bin(int blk, const int* __restrict__ src,
                                        const int* __restrict__ dst,
                                        const int* __restrict__ et,
                                        unsigned* __restrict__ bucketFill,
                                        unsigned long long* __restrict__ staging) {
    __shared__ unsigned lhist[NBUCK];
    __shared__ unsigned lstart[NBUCK];
    __shared__ unsigned gbase[NBUCK];
    __shared__ unsigned scan_tmp[NBUCK];
    __shared__ unsigned long long lval[BIN_EPB];
    __shared__ unsigned ltgt[BIN_EPB];
    int tid = threadIdx.x;
    int base = blk * BIN_EPB;
    int n = N_EDGES - base; if (n > BIN_EPB) n = BIN_EPB;

    for (int i = tid; i < NBUCK; i += 256) lhist[i] = 0;
    __syncthreads();

    unsigned bb[4], rr[4];
    unsigned long long vv[4];
#pragma unroll
    for (int j = 0; j < 4; ++j) {
        int i = j * 256 + tid;
        bb[j] = 0xFFFFFFFFu;
        if (i < n) {
            int e = base + i;
            unsigned d = (unsigned)dst[e];
            unsigned b = d >> BSHIFT;
            bb[j] = b;
            rr[j] = atomicAdd(&lhist[b], 1u);
            vv[j] = ((unsigned long long)d << 32) |
                    (unsigned long long)((unsigned)src[e] | ((unsigned)et[e] << 17));
        }
    }
    __syncthreads();
    unsigned v0 = (tid < NBUCK) ? lhist[tid] : 0;
    if (tid < NBUCK) scan_tmp[tid] = v0;
    __syncthreads();
    for (int s = 1; s < NBUCK; s <<= 1) {
        unsigned t = 0;
        if (tid < NBUCK && tid >= (unsigned)s) t = scan_tmp[tid - s];
        __syncthreads();
        if (tid < NBUCK) scan_tmp[tid] += t;
        __syncthreads();
    }
    if (tid < NBUCK) {
        lstart[tid] = scan_tmp[tid] - v0;
        gbase[tid] = (v0 > 0) ? atomicAdd(&bucketFill[tid], v0) : 0u;
    }
    __syncthreads();
#pragma unroll
    for (int j = 0; j < 4; ++j) {
        if (bb[j] != 0xFFFFFFFFu) {
            unsigned pos = lstart[bb[j]] + rr[j];
            unsigned off = gbase[bb[j]] + rr[j];
            lval[pos] = vv[j];
            ltgt[pos] = (off < BCAP) ? (bb[j] * BCAP + off) : 0xFFFFFFFFu;
        }
    }
    __syncthreads();
    for (int i = tid; i < n; i += 256) {
        unsigned t = ltgt[i];
        if (t != 0xFFFFFFFFu) staging[t] = lval[i];
    }
}

// ---- pack job body: basis[5][KL][50] + root[KL][50] -> MFMA B-fragment order
__device__ __forceinline__ void job_pack(int blk, const void* basis, const void* root,
                                         bf16* Wb, int KL, int isbf) {
    int g = blk * 256 + threadIdx.x;
    int ks = g / 10240;
    int r = g - ks * 10240;
    int ct = r >> 9;
    int r2 = r & 511;
    int l = r2 >> 3, j = r2 & 7;
    int k = ks * 32 + ((l >> 4) << 3) + j;
    int n = ct * 16 + (l & 15);
    float v = 0.f;
    if (k < KL && n < 300) {
        if (n < 250) { int b = n / 50, f = n - b * 50; v = ldw(basis, (b * KL + k) * 50 + f, isbf); }
        else         v = ldw(root, k * 50 + (n - 250), isbf);
    }
    Wb[g] = f2b(v);
}

// ---- rel job: per-type rt1/rt2/c8 tables from raw weights (templated dtype)
template<int ISBF>
__device__ __forceinline__ void job_rel(int t,
        const void* __restrict__ rel_emb, const void* __restrict__ rel_w,
        const void* __restrict__ basis1, const void* __restrict__ comp1,
        const void* __restrict__ basis2, const void* __restrict__ comp2,
        float* __restrict__ rt1, float* __restrict__ rt2,
        float* __restrict__ c81, float* __restrict__ c82) {
    int tid = threadIdx.x;
    __shared__ float rf[D_IN];
    __shared__ float r2s[D_HID];
    int tm = (t >= N_REL) ? t - N_REL : t;
    if (tid < D_IN) rf[tid] = ldw(rel_emb, tm * D_IN + tid, ISBF);
    if (tid < 8) {
        c81[t * 8 + tid] = (tid < 5) ? ldw(comp1, t * 5 + tid, ISBF) : 0.f;
        c82[t * 8 + tid] = (tid < 5) ? ldw(comp2, t * 5 + tid, ISBF) : 0.f;
    }
    __syncthreads();
    if (tid < 50) {
        int f = tid;
        float a = 0.f;
        for (int b = 0; b < 5; ++b) {
            float cb = ldw(comp1, t * 5 + b, ISBF);
            float s = 0.f;
            for (int k = 0; k < D_IN; ++k) s += rf[k] * ldw(basis1, (b * D_IN + k) * 50 + f, ISBF);
            a += cb * s;
        }
        rt1[t * 50 + f] = a;
        float s2 = 0.f;
        for (int k = 0; k < D_IN; ++k) s2 += rf[k] * ldw(rel_w, k * 50 + f, ISBF);
        r2s[f] = s2;
    }
    __syncthreads();
    if (tid < 50) {
        int f = tid;
        float a = 0.f;
        for (int b = 0; b < 5; ++b) {
            float cb = ldw(comp2, t * 5 + b, ISBF);
            float s = 0.f;
            for (int k = 0; k < 50; ++k) s += r2s[k] * ldw(basis2, (b * 50 + k) * 50 + f, ISBF);
            a += cb * s;
        }
        rt2[t * 50 + f] = a;
    }
}

// ================= fused mid kernel: bin | pack1 | pack2 | rel ===============
// pack/rel blocks self-detect dtype (no serial k_detect launch); the first
// pack1 block also publishes flag[0] for downstream kernels (stream-ordered).
__global__ __launch_bounds__(256) void k_mid(const int* __restrict__ srcp,
                                             const int* __restrict__ dstp,
                                             const int* __restrict__ etp,
                                             unsigned* __restrict__ bucketFill,
                                             unsigned long long* __restrict__ staging,
                                             const void* __restrict__ x_raw,
                                             int* __restrict__ flag,
                                             const void* rel_emb, const void* rel_w,
                                             const void* basis1, const void* comp1,
                                             const void* root1,
                                             const void* basis2, const void* comp2,
                                             const void* root2,
                                             bf16* __restrict__ Wb1, bf16* __restrict__ Wb2,
                                             float* __restrict__ rt1, float* __restrict__ rt2,
                                             float* __restrict__ c81, float* __restrict__ c82) {
    int blk = blockIdx.x;
    if (blk < BIN_BLKS) { job_bin(blk, srcp, dstp, etp, bucketFill, staging); return; }
    blk -= BIN_BLKS;
    int isbf = detect_flag((const unsigned short*)x_raw);
    if (blk < MID_PACK1_BLKS) {
        if (blk == 0 && threadIdx.x == 0) flag[0] = isbf;
        job_pack(blk, basis1, root1, Wb1, D_IN, isbf);
        return;
    }
    blk -= MID_PACK1_BLKS;
    if (blk < MID_PACK2_BLKS) { job_pack(blk, basis2, root2, Wb2, D_HID, isbf); return; }
    blk -= MID_PACK2_BLKS;
    if (isbf) job_rel<1>(blk, rel_emb, rel_w, basis1, comp1, basis2, comp2, rt1, rt2, c81, c82);
    else      job_rel<0>(blk, rel_emb, rel_w, basis1, comp1, basis2, comp2, rt1, rt2, c81, c82);
}

// ---- per-bucket CSR build, 256-thread version (shares LDS with gemm) --------
__device__ __forceinline__ void job_bucket(int b, char* shraw,
        const unsigned long long* __restrict__ staging,
        const unsigned* __restrict__ bucketFill,
        int* __restrict__ offs, unsigned* __restrict__ se) {
    unsigned* hist = (unsigned*)shraw;          // [512]
    unsigned* excl = hist + 512;                // [512]
    unsigned* bfs  = excl + 512;                // [256] (196 used)
    unsigned* tmp  = bfs + 256;                 // [256]
    int tid = threadIdx.x;

    if (tid < NBUCK) {
        unsigned c = bucketFill[tid];
        bfs[tid] = (c > BCAP) ? BCAP : c;
    }
    hist[tid] = 0; hist[tid + 256] = 0;
    __syncthreads();
    // inclusive scan of 196 bucket totals
    for (int s = 1; s < NBUCK; s <<= 1) {
        unsigned t = 0;
        if (tid < NBUCK && tid >= s) t = bfs[tid - s];
        __syncthreads();
        if (tid < NBUCK) bfs[tid] += t;
        __syncthreads();
    }
    unsigned base = (b == 0) ? 0u : bfs[b - 1];
    unsigned cnt = bfs[b] - base;

    const unsigned long long* p = staging + (size_t)b * BCAP;
    // pass 1: per-node histogram (local id = dst & 511)
    for (unsigned i = tid; i < cnt; i += 256) {
        unsigned d = (unsigned)(p[i] >> 32);
        atomicAdd(&hist[d & 511], 1u);
    }
    __syncthreads();
    // scan 512 node counts with 256 threads (pairwise)
    unsigned h0 = hist[2 * tid], h1 = hist[2 * tid + 1];
    tmp[tid] = h0 + h1;
    __syncthreads();
    for (int s = 1; s < 256; s <<= 1) {
        unsigned t = (tid >= s) ? tmp[tid - s] : 0u;
        __syncthreads();
        tmp[tid] += t;
        __syncthreads();
    }
    unsigned pe = (tid > 0) ? tmp[tid - 1] : 0u;
    excl[2 * tid]     = pe;
    excl[2 * tid + 1] = pe + h0;
    hist[2 * tid] = 0; hist[2 * tid + 1] = 0;   // reset for rank pass
    __syncthreads();

#pragma unroll
    for (int q = 0; q < 2; ++q) {
        int li = 2 * tid + q;
        int node = b * 512 + li;
        if (node < N_NODES) offs[node] = (int)(base + excl[li]);
        if (node == N_NODES - 1) offs[N_NODES] = (int)(base + cnt);
    }

    // pass 2: scatter with per-node rank
    for (unsigned i = tid; i < cnt; i += 256) {
        unsigned long long v = p[i];
        unsigned ld = ((unsigned)(v >> 32)) & 511u;
        unsigned r = atomicAdd(&hist[ld], 1u);
        se[base + excl[ld] + r] = (unsigned)v;
    }
}

// ---- MFMA GEMM (+ fused bucket blocks, scheduled FIRST): X @ Wb -> Y8 + R
// 32-row block, 4 waves = 2(row) x 2(col-half). Each wave: acc[10] = 40 AGPR.
template<int KP, bool ZT, bool RAWX>
__global__ __launch_bounds__(256, 4) void k_gemm_b(const void* __restrict__ Xraw,
                                                const int* __restrict__ flag,
                                                const bf16* __restrict__ Wb,
                                                unsigned char* __restrict__ Y8,
                                                bf16* __restrict__ R, int M,
                                                const int* __restrict__ tgt,
                                                const unsigned long long* __restrict__ staging,
                                                const unsigned* __restrict__ bucketFill,
                                                int* __restrict__ offs,
                                                unsigned* __restrict__ se,
                                                int nbuckBlks) {
    constexpr int AP = KP + 8;        // padded A-tile leading dim (bf16 elems)
    constexpr int CBYTES = 32 * CST * 2;   // 20736
    constexpr int ABYTES = 32 * AP * 2;
    __shared__ __attribute__((aligned(16))) char shraw[CBYTES + ABYTES];
    if ((int)blockIdx.x < nbuckBlks) {
        job_bucket(blockIdx.x, shraw, staging, bucketFill, offs, se);
        return;
    }
    int gblk = blockIdx.x - nbuckBlks;
    bf16* smemC = (bf16*)shraw;
    bf16* smemA = (bf16*)(shraw + CBYTES);
    int tid = threadIdx.x;
    int w = tid >> 6, lane = tid & 63;
    int quad = lane >> 4, cIn = lane & 15;
    int rw = w & 1, cw = w >> 1;      // row-wave, col-half wave
    int base_row = gblk * 32;

    if (RAWX) {
        int isbf = flag[0];
        // 32 rows x 128 cols (zero-pad 100..127), 4 cols/thread (8/16B loads)
        for (int i = tid; i < 32 * 32; i += 256) {
            int r = i >> 5, c4 = (i & 31) << 2;
            int row = base_row + r; if (row > M - 1) row = M - 1;
            unsigned p0 = 0, p1 = 0;
            if (c4 < 100) {
                if (isbf) {
                    const unsigned* xp = (const unsigned*)((const unsigned short*)Xraw + (size_t)row * 100 + c4);
                    p0 = xp[0]; p1 = xp[1];
                } else {
                    const float* xp = (const float*)Xraw + (size_t)row * 100 + c4;
                    float4 v = *(const float4*)xp;
                    bf16 b0 = f2b(v.x), b1 = f2b(v.y), b2 = f2b(v.z), b3 = f2b(v.w);
                    p0 = (unsigned)*(unsigned short*)&b0 | ((unsigned)*(unsigned short*)&b1 << 16);
                    p1 = (unsigned)*(unsigned short*)&b2 | ((unsigned)*(unsigned short*)&b3 << 16);
                }
            }
            unsigned* dstp2 = (unsigned*)(&smemA[r * AP + c4]);
            dstp2[0] = p0; dstp2[1] = p1;
        }
    } else {
        const bf16* X = (const bf16*)Xraw;
        const int TOT = 32 * KP / 8;
        for (int i = tid; i < TOT; i += 256) {
            int e8 = i * 8;
            int r = e8 / KP, c = e8 - r * KP;
            int row = base_row + r; if (row > M - 1) row = M - 1;
            *(uint4*)(&smemA[r * AP + c]) = *(const uint4*)(&X[(size_t)row * KP + c]);
        }
    }
    __syncthreads();

    f32x4 acc[10];
#pragma unroll
    for (int i = 0; i < 10; ++i) acc[i] = (f32x4){0.f, 0.f, 0.f, 0.f};

#pragma unroll
    for (int ks = 0; ks < KP / 32; ++ks) {
        short8 a = *(const short8*)(&smemA[(rw * 16 + cIn) * AP + ks * 32 + quad * 8]);
#pragma unroll
        for (int ct = 0; ct < 10; ++ct) {
            short8 b = *(const short8*)(&Wb[(size_t)((ks * 20 + cw * 10 + ct) * 64 + lane) * 8]);
            acc[ct] = __builtin_amdgcn_mfma_f32_16x16x32_bf16(a, b, acc[ct], 0, 0, 0);
        }
    }

#pragma unroll
    for (int ct = 0; ct < 10; ++ct)
#pragma unroll
        for (int r = 0; r < 4; ++r)
            smemC[(rw * 16 + quad * 4 + r) * CST + (cw * 10 + ct) * 16 + cIn] = f2b(acc[ct][r]);
    __syncthreads();

    int tv = -1;
    if (ZT) tv = tgt[0];
    int valid = M - base_row; if (valid > 32) valid = 32;

    for (int i = tid; i < valid * 64; i += 256) {
        int r = i >> 6, u = i & 63;
        int row = base_row + r;
        unsigned pbits;
        if (u < 50) {
            pbits = pk4_f8(b2f(smemC[r * CST + u]),       b2f(smemC[r * CST + 50 + u]),
                           b2f(smemC[r * CST + 100 + u]), b2f(smemC[r * CST + 150 + u]));
        } else if (u < 63) {
            int fb = (u - 50) * 4;
            float v0 = (fb + 0 < 50) ? b2f(smemC[r * CST + 200 + fb + 0]) : 0.f;
            float v1 = (fb + 1 < 50) ? b2f(smemC[r * CST + 200 + fb + 1]) : 0.f;
            float v2 = (fb + 2 < 50) ? b2f(smemC[r * CST + 200 + fb + 2]) : 0.f;
            float v3 = (fb + 3 < 50) ? b2f(smemC[r * CST + 200 + fb + 3]) : 0.f;
            pbits = pk4_f8(v0, v1, v2, v3);
        } else {
            pbits = 0u;
        }
        if (ZT && row == tv) pbits = 0u;
        *(unsigned*)(Y8 + (size_t)row * 256 + u * 4) = pbits;
    }
    for (int i = tid; i < valid * 32; i += 256) {
        int r = i >> 5, cu = i & 31;
        int row = base_row + r;
        int j0 = cu * 2, j1 = j0 + 1;
        unsigned short ua = (j0 < 50) ? *(const unsigned short*)&smemC[r * CST + 250 + j0] : 0;
        unsigned short ub = (j1 < 50) ? *(const unsigned short*)&smemC[r * CST + 250 + j1] : 0;
        unsigned u = (unsigned)ua | ((unsigned)ub << 16);
        if (ZT && row == tv) u = 0u;
        *(unsigned*)((unsigned short*)R + (size_t)row * 64 + j0) = u;
    }
}

// ================= per-node gather-reduce (no atomics) =======================
__device__ __forceinline__ void edge_body(unsigned p, int f,
        const unsigned char* __restrict__ Y8,
        const float* __restrict__ c8, const float* __restrict__ rt,
        f32x2& acc2, float& accS) {
    unsigned ps = (unsigned)__builtin_amdgcn_readfirstlane((int)p);
    int s_ = (int)(ps & 0x1FFFFu);
    int t_ = (int)(ps >> 17);
    const unsigned char* yr = Y8 + (size_t)s_ * 256;
    unsigned a4 = *(const unsigned*)(yr + 4 * f);
    float y4 = f8tof(yr[200 + f]);
    const float* cp = c8 + t_ * 8;
    f32x4 c03 = *(const f32x4*)cp;
    float c4 = cp[4];
    float rv = rt[t_ * 50 + f];
    f32x2 y01 = f8pk<false>(a4);
    f32x2 y23 = f8pk<true>(a4);
    f32x2 cA; cA.x = c03.x; cA.y = c03.y;
    f32x2 cB; cB.x = c03.z; cB.y = c03.w;
    acc2 += cA * y01;
    acc2 += cB * y23;
    accS += rv + c4 * y4;
}

// Two consecutive rows per wave, edge loops interleaved 4-deep (proven form;
// compiler's own scheduling beats manual scalar-prefetch, r13 post-mortem).
__device__ __forceinline__ void pair_reduce(const int* __restrict__ off,
        const unsigned int* __restrict__ se, const float* __restrict__ c8,
        const float* __restrict__ rt, const unsigned char* __restrict__ Y8,
        int rowA, int f, float& outA, float& outB, float& cntA, float& cntB) {
    int e0 = __builtin_amdgcn_readfirstlane(off[rowA]);
    int e1 = __builtin_amdgcn_readfirstlane(off[rowA + 1]);
    int e2 = __builtin_amdgcn_readfirstlane(off[rowA + 2]);
    f32x2 a2A; a2A.x = 0.f; a2A.y = 0.f;
    f32x2 a2B; a2B.x = 0.f; a2B.y = 0.f;
    float sA = 0.f, sB = 0.f;
    int eA = e0, eB = e1;
    while (eA + 4 <= e1 && eB + 4 <= e2) {
        unsigned pA0 = se[eA],     pA1 = se[eA + 1], pA2 = se[eA + 2], pA3 = se[eA + 3];
        unsigned pB0 = se[eB],     pB1 = se[eB + 1], pB2 = se[eB + 2], pB3 = se[eB + 3];
        edge_body(pA0, f, Y8, c8, rt, a2A, sA);
        edge_body(pB0, f, Y8, c8, rt, a2B, sB);
        edge_body(pA1, f, Y8, c8, rt, a2A, sA);
        edge_body(pB1, f, Y8, c8, rt, a2B, sB);
        edge_body(pA2, f, Y8, c8, rt, a2A, sA);
        edge_body(pB2, f, Y8, c8, rt, a2B, sB);
        edge_body(pA3, f, Y8, c8, rt, a2A, sA);
        edge_body(pB3, f, Y8, c8, rt, a2B, sB);
        eA += 4; eB += 4;
    }
    while (eA + 4 <= e1) {
        unsigned p0 = se[eA], p1 = se[eA + 1], p2 = se[eA + 2], p3 = se[eA + 3];
        edge_body(p0, f, Y8, c8, rt, a2A, sA);
        edge_body(p1, f, Y8, c8, rt, a2A, sA);
        edge_body(p2, f, Y8, c8, rt, a2A, sA);
        edge_body(p3, f, Y8, c8, rt, a2A, sA);
        eA += 4;
    }
    while (eB + 4 <= e2) {
        unsigned p0 = se[eB], p1 = se[eB + 1], p2 = se[eB + 2], p3 = se[eB + 3];
        edge_body(p0, f, Y8, c8, rt, a2B, sB);
        edge_body(p1, f, Y8, c8, rt, a2B, sB);
        edge_body(p2, f, Y8, c8, rt, a2B, sB);
        edge_body(p3, f, Y8, c8, rt, a2B, sB);
        eB += 4;
    }
    for (; eA < e1; ++eA) edge_body(se[eA], f, Y8, c8, rt, a2A, sA);
    for (; eB < e2; ++eB) edge_body(se[eB], f, Y8, c8, rt, a2B, sB);
    outA = a2A.x + a2A.y + sA;
    outB = a2B.x + a2B.y + sB;
    float nA = (float)(e1 - e0); cntA = nA > 1.f ? nA : 1.f;
    float nB = (float)(e2 - e1); cntB = nB > 1.f ? nB : 1.f;
}

// Layer 1: h[row][0..63] = mean_agg + x@root (R) + bias (cols>=50 zero)
__global__ __launch_bounds__(256) void k_reduce1(const int* __restrict__ off,
                                                 const unsigned int* __restrict__ se,
                                                 const float* __restrict__ c8,
                                                 const float* __restrict__ rt,
                                                 const unsigned char* __restrict__ Y8,
                                                 const bf16* __restrict__ R,
                                                 const void* __restrict__ bias_raw,
                                                 const int* __restrict__ flag,
                                                 bf16* __restrict__ h) {
    int wid = threadIdx.x >> 6, lane = threadIdx.x & 63;
    int rowA = __builtin_amdgcn_readfirstlane(blockIdx.x * 8 + wid * 2);
    int f = (lane < 50) ? lane : 49;
    float accA, accB, cntA, cntB;
    pair_reduce(off, se, c8, rt, Y8, rowA, f, accA, accB, cntA, cntB);
    float bv = ldw(bias_raw, f, flag[0]);
    float vA = accA / cntA + b2f(R[(size_t)rowA * 64 + f]) + bv;
    float vB = accB / cntB + b2f(R[(size_t)(rowA + 1) * 64 + f]) + bv;
    h[(size_t)rowA * 64 + lane]       = f2b(lane < 50 ? vA : 0.f);
    h[(size_t)(rowA + 1) * 64 + lane] = f2b(lane < 50 ? vB : 0.f);
}

__device__ __forceinline__ void softmax_store(float acc, float cnt, int row, int f,
        int lane, const bf16* __restrict__ R, float bv,
        int isbf, void* __restrict__ out) {
    float v = -INFINITY;
    if (lane < 50)
        v = acc / cnt + b2f(R[(size_t)row * 64 + f]) + bv;
    float m = v;
    for (int o = 32; o > 0; o >>= 1) m = fmaxf(m, __shfl_xor(m, o));
    float ex = (lane < 50) ? expf(v - m) : 0.f;
    float s = ex;
    for (int o = 32; o > 0; o >>= 1) s += __shfl_xor(s, o);
    float res = v - m - logf(s);
    if (lane < 50) {
        if (isbf) ((bf16*)out)[row * 50 + f] = f2b(res);
        else      ((float*)out)[row * 50 + f] = res;
    }
}

// Layer 2: same reduce + log_softmax epilogue; dual-dtype output store.
__global__ __launch_bounds__(256) void k_reduce2(const int* __restrict__ off,
                                                 const unsigned int* __restrict__ se,
                                                 const float* __restrict__ c8,
                                                 const float* __restrict__ rt,
                                                 const unsigned char* __restrict__ Y8,
                                                 const bf16* __restrict__ R,
                                                 const void* __restrict__ bias_raw,
                                                 const int* __restrict__ flag,
                                                 void* __restrict__ out) {
    int wid = threadIdx.x >> 6, lane = threadIdx.x & 63;
    int rowA = __builtin_amdgcn_readfirstlane(blockIdx.x * 8 + wid * 2);
    int f = (lane < 50) ? lane : 49;
    float accA, accB, cntA, cntB;
    pair_reduce(off, se, c8, rt, Y8, rowA, f, accA, accB, cntA, cntB);
    int isbf = flag[0];
    float bv = ldw(bias_raw, f, isbf);
    softmax_store(accA, cntA, rowA, f, lane, R, bv, isbf, out);
    softmax_store(accB, cntB, rowA + 1, f, lane, R, bv, isbf, out);
}

extern "C" void kernel_launch(void* const* d_in, const int* in_sizes, int n_in,
                              void* d_out, int out_size, void* d_ws, size_t ws_size,
                              hipStream_t stream) {
    const void* x_raw = d_in[0];
    const int*  ei    = (const int*)d_in[1];
    const int*  et    = (const int*)d_in[2];
    const int*  tgt   = (const int*)d_in[3];
    const void* rel_emb = d_in[4];
    const void* rel_w   = d_in[5];
    const void* basis1  = d_in[6];
    const void* comp1   = d_in[7];
    const void* root1   = d_in[8];
    const void* bias1   = d_in[9];
    const void* basis2  = d_in[10];
    const void* comp2   = d_in[11];
    const void* root2   = d_in[12];
    const void* bias2   = d_in[13];

    char* wsp = (char*)d_ws;
    size_t off_b = 0;
    auto alloc = [&](size_t bytes) {
        void* p = wsp + off_b;
        off_b = (off_b + bytes + 255) & ~(size_t)255;
        return p;
    };
    unsigned char* Y8 = (unsigned char*)alloc((size_t)N_NODES * 256);       // 25.6 MB
    bf16*  R    = (bf16*) alloc((size_t)N_NODES * 64 * sizeof(bf16));       // 12.8 MB
    bf16*  h    = (bf16*) alloc((size_t)N_NODES * 64 * sizeof(bf16));       // 12.8 MB
    unsigned int* se = (unsigned int*)alloc((size_t)N_EDGES * sizeof(unsigned int)); // 6.4 MB
    unsigned long long* staging = (unsigned long long*)alloc((size_t)NBUCK * BCAP * 8); // 16 MB
    int*   offs = (int*)  alloc((size_t)(N_NODES + 1) * sizeof(int));
    unsigned* bucketFill = (unsigned*)alloc((size_t)NBUCK * sizeof(unsigned));
    bf16*  Wb1  = (bf16*) alloc((size_t)40960 * sizeof(bf16));
    bf16*  Wb2  = (bf16*) alloc((size_t)20480 * sizeof(bf16));
    float* rt1  = (float*)alloc((size_t)N_REL2 * 50 * sizeof(float));
    float* rt2  = (float*)alloc((size_t)N_REL2 * 50 * sizeof(float));
    float* c81  = (float*)alloc((size_t)N_REL2 * 8 * sizeof(float));
    float* c82  = (float*)alloc((size_t)N_REL2 * 8 * sizeof(float));
    int*   flag = (int*)  alloc(sizeof(int));

    const int* srcp = ei;
    const int* dstp = ei + N_EDGES;

    hipMemsetAsync(bucketFill, 0, (size_t)NBUCK * sizeof(unsigned), stream);

    // bin | pack1 | pack2 | rel (pack/rel self-detect dtype; pack1 blk0 writes flag)
    k_mid<<<MID_TOTAL, 256, 0, stream>>>(srcp, dstp, et, bucketFill, staging,
                                         x_raw, flag,
                                         rel_emb, rel_w, basis1, comp1, root1,
                                         basis2, comp2, root2,
                                         Wb1, Wb2, rt1, rt2, c81, c82);

    // Layer-1 GEMM (raw-x staging) fused with per-bucket CSR build (buckets first)
    k_gemm_b<128, true, true><<<GEMM_BLKS + NBUCK, 256, 0, stream>>>(
        x_raw, flag, Wb1, Y8, R, N_NODES, tgt, staging, bucketFill, offs, se, NBUCK);

    k_reduce1<<<RED_BLKS, 256, 0, stream>>>(offs, se, c81, rt1, Y8, R, bias1, flag, h);

    // Layer-2 GEMM (h is our aligned bf16 layout)
    k_gemm_b<64, false, false><<<GEMM_BLKS, 256, 0, stream>>>(
        h, flag, Wb2, Y8, R, N_NODES, nullptr, staging, bucketFill, offs, se, 0);

    k_reduce2<<<RED_BLKS, 256, 0, stream>>>(offs, se, c82, rt2, Y8, R, bias2, flag, d_out);
}